// Round 15
// baseline (241.139 us; speedup 1.0000x reference)
//
#include <hip/hip_runtime.h>
#include <hip/hip_bf16.h>
#include <stdint.h>

#define NQ 32
#define NCLS 5
#define SHOT 5
#define NIMG 57          // 32 query + 25 support
#define P1 7056          // 84*84
#define P2 1764          // 42*42
#define P3 441           // 21*21
#define PX 3528          // x-pooled stage-1 grid: 84 rows x 42
#define MM (SHOT*P3)     // 2205
#define EPSB 1e-5f
#define SLOPE 0.2f
#define NEGINF -3.4e38f
#define NREP 32          // stats atomic replication factor
#define MSPAN 576        // sim m-range rows per block (36 tiles)
#define MRNG 4           // m-ranges (4*576 >= 2205)
#define SLS 88           // sim LDS row stride in ushorts

typedef __attribute__((ext_vector_type(8))) short short8;
typedef __attribute__((ext_vector_type(4))) float f32x4;

__device__ inline float ldf(const float* p) { return *p; }
__device__ inline float ldf(const __hip_bfloat16* p) { return __bfloat162float(*p); }
__device__ inline void stf(float* p, float v) { *p = v; }
__device__ inline void stf(__hip_bfloat16* p, float v) { *p = __float2bfloat16(v); }

__device__ __forceinline__ unsigned short bf16bits(float v)
{
    __hip_bfloat16 h = __float2bfloat16(v);
    return *reinterpret_cast<unsigned short*>(&h);
}
__device__ __forceinline__ float bits2f(unsigned short u)
{
    unsigned int x = ((unsigned int)u) << 16;
    return *reinterpret_cast<float*>(&x);
}

// ---------------- all weight packs + zero stats sums, one launch ----------------
__global__ void pack_all_k(const float* __restrict__ w1, const float* __restrict__ w2,
                           const float* __restrict__ w3, const float* __restrict__ w4,
                           unsigned short* __restrict__ wpk1, unsigned short* __restrict__ wpk2,
                           unsigned short* __restrict__ wpk3, unsigned short* __restrict__ wpk4,
                           float* __restrict__ sums)
{
    int i = blockIdx.x * 256 + threadIdx.x;
    if (i < 4 * 6 * 64 * 2 * NREP) sums[i] = 0.f;   // zero all 4 stages' stat sums
    if (i < 3 * 36864) {
        int set = i / 36864, ii = i - set * 36864;
        const float* w = (set == 0) ? w2 : (set == 1) ? w3 : w4;
        unsigned short* wpk = (set == 0) ? wpk2 : (set == 1) ? wpk3 : wpk4;
        int j = ii & 7, lane = (ii >> 3) & 63, chunk = ii >> 9;
        int nt = chunk & 3, half = (chunk >> 2) & 1, t = chunk >> 3;
        int co = nt * 16 + (lane & 15);
        int ci = half * 32 + (lane >> 4) * 8 + j;
        wpk[ii] = bf16bits(w[co * 576 + ci * 9 + t]);
    } else {
        int ii = i - 3 * 36864;
        if (ii >= 4096) return;
        int j = ii & 7, lane = (ii >> 3) & 63, c8 = ii >> 9;
        int nt = c8 & 3, f = c8 >> 2;
        int co = nt * 16 + (lane & 15), q = lane >> 4;
        int k = q * 8 + j;
        float val = 0.f;
        if (f == 0) {
            int t = k >> 2, ci = k & 3;
            if (ci < 3) val = w1[co * 27 + ci * 9 + t];
        } else if (k < 4) {
            int ci = k & 3;
            if (ci < 3) val = w1[co * 27 + ci * 9 + 8];
        }
        wpk1[ii] = bf16bits(val);
    }
}

// ---------------- MFMA conv1 3->64, fused BN stats + in-register x-pair max ----------------
__global__ __launch_bounds__(256) void conv1m_k(const float* __restrict__ in1,
                                                const float* __restrict__ in2,
                                                const unsigned short* __restrict__ wpk1,
                                                __hip_bfloat16* __restrict__ xpool,
                                                float* __restrict__ sums)
{
    constexpr int S = 84, P = P1, MBLK = 256, NB = 28, SPAN = MBLK + 2 * S + 2;  // 426
    __shared__ __align__(16) unsigned short ls4[SPAN * 4];   // 8 B per pixel [c0,c1,c2,0]
    __shared__ float qs[4][64], qs2[4][64];
    int img = blockIdx.x / NB;
    int p0 = (blockIdx.x % NB) * MBLK;
    int tid = threadIdx.x, lane = tid & 63, wv = tid >> 6;
    int col = lane & 15, quad = lane >> 4;
    const float* in = (img < NQ) ? in1 + (size_t)img * 3 * P1
                                 : in2 + (size_t)(img - NQ) * 3 * P1;
    for (int u = tid; u < SPAN; u += 256) {
        int p = p0 - S - 1 + u;
        union { unsigned short us[4]; uint2 u2; } o;
        o.u2 = (uint2){0u, 0u};
        if (p >= 0 && p < P) {
            o.us[0] = bf16bits(in[p]);
            o.us[1] = bf16bits(in[P1 + p]);
            o.us[2] = bf16bits(in[2 * P1 + p]);
        }
        *(uint2*)(ls4 + u * 4) = o.u2;
    }
    const short8* wb = (const short8*)wpk1;
    short8 b0[4], b1[4];
    #pragma unroll
    for (int nt = 0; nt < 4; ++nt) {
        b0[nt] = wb[(size_t)(nt * 64 + lane)];
        b1[nt] = wb[(size_t)((4 + nt) * 64 + lane)];
    }
    int t0 = 2 * quad, t1 = t0 + 1;
    int d0 = (t0 / 3 - 1) * S + (t0 % 3 - 1);
    int d1 = (t1 / 3 - 1) * S + (t1 % 3 - 1);
    const int d8 = S + 1;
    int tx0 = t0 % 3, tx1 = t1 % 3;
    __syncthreads();
    f32x4 acc[4][4];
    #pragma unroll
    for (int mt = 0; mt < 4; ++mt)
        #pragma unroll
        for (int nt = 0; nt < 4; ++nt) acc[mt][nt] = (f32x4){0.f, 0.f, 0.f, 0.f};
    #pragma unroll
    for (int mt = 0; mt < 4; ++mt) {
        int pl = wv * 64 + mt * 16 + col;
        int xm = (p0 + pl) % S;
        int base = pl + S + 1;
        uint2 h0 = *(const uint2*)(ls4 + (base + d0) * 4);
        uint2 h1 = *(const uint2*)(ls4 + (base + d1) * 4);
        uint2 h8 = *(const uint2*)(ls4 + (base + d8) * 4);
        bool ok0 = (tx0 == 0) ? (xm >= 1) : ((tx0 == 2) ? (xm <= S - 2) : true);
        bool ok1 = (tx1 == 0) ? (xm >= 1) : ((tx1 == 2) ? (xm <= S - 2) : true);
        bool ok8 = (quad == 0) && (xm <= S - 2);
        if (!ok0) h0 = (uint2){0u, 0u};
        if (!ok1) h1 = (uint2){0u, 0u};
        if (!ok8) h8 = (uint2){0u, 0u};
        union { uint4 u; short8 s; } ca, cb;
        ca.u = (uint4){h0.x, h0.y, h1.x, h1.y};
        cb.u = (uint4){h8.x, h8.y, 0u, 0u};
        #pragma unroll
        for (int nt = 0; nt < 4; ++nt) {
            acc[mt][nt] = __builtin_amdgcn_mfma_f32_16x16x32_bf16(ca.s, b0[nt], acc[mt][nt], 0, 0, 0);
            acc[mt][nt] = __builtin_amdgcn_mfma_f32_16x16x32_bf16(cb.s, b1[nt], acc[mt][nt], 0, 0, 0);
        }
    }
    float s[4] = {0.f, 0.f, 0.f, 0.f}, s2[4] = {0.f, 0.f, 0.f, 0.f};
    __hip_bfloat16* ob = xpool + (size_t)img * PX * 64;
    #pragma unroll
    for (int mt = 0; mt < 4; ++mt) {
        int tb = p0 + wv * 64 + mt * 16 + quad * 4;
        #pragma unroll
        for (int reg = 0; reg < 4; ++reg) {
            int pr = tb + reg;
            if (pr < P) {
                #pragma unroll
                for (int nt = 0; nt < 4; ++nt) {
                    float v = acc[mt][nt][reg];
                    s[nt] += v;
                    s2[nt] = fmaf(v, v, s2[nt]);
                }
            }
        }
        #pragma unroll
        for (int pr2 = 0; pr2 < 2; ++pr2) {
            int m0 = tb + pr2 * 2;
            if (m0 < P) {
                #pragma unroll
                for (int nt = 0; nt < 4; ++nt) {
                    float v = fmaxf(acc[mt][nt][pr2 * 2], acc[mt][nt][pr2 * 2 + 1]);
                    ob[(size_t)(m0 >> 1) * 64 + nt * 16 + col] = __float2bfloat16(v);
                }
            }
        }
    }
    #pragma unroll
    for (int d = 16; d < 64; d <<= 1)
        #pragma unroll
        for (int nt = 0; nt < 4; ++nt) {
            s[nt] += __shfl_xor(s[nt], d, 64);
            s2[nt] += __shfl_xor(s2[nt], d, 64);
        }
    if (quad == 0) {
        #pragma unroll
        for (int nt = 0; nt < 4; ++nt) {
            qs[wv][nt * 16 + col] = s[nt];
            qs2[wv][nt * 16 + col] = s2[nt];
        }
    }
    __syncthreads();
    if (wv == 0) {
        int g = (img < NQ) ? 0 : 1 + (img - NQ) / SHOT;
        int rep = blockIdx.x & (NREP - 1);
        float ts = qs[0][lane] + qs[1][lane] + qs[2][lane] + qs[3][lane];
        float ts2 = qs2[0][lane] + qs2[1][lane] + qs2[2][lane] + qs2[3][lane];
        float* base = sums + ((size_t)(g * 64 + lane) * 2) * NREP + rep;
        atomicAdd(base, ts);
        atomicAdd(base + NREP, ts2);
    }
}

// ---------------- y-pair max + BN + LeakyReLU on x-pooled raw -> pooled1 bf16 --------------
__global__ __launch_bounds__(256) void bnpooly_k(const unsigned short* __restrict__ in,
                                                 const float* __restrict__ ms,
                                                 unsigned short* __restrict__ out)
{
    int i = blockIdx.x * 256 + threadIdx.x;
    if (i >= NIMG * P2 * 16) return;       // ushort4 groups
    int q4 = i & 15;
    int t = i >> 4;
    int p = t % P2;
    int img = t / P2;
    int y = p / 42, x2 = p - y * 42;
    int g = (img < NQ) ? 0 : 1 + (img - NQ) / SHOT;
    size_t base = ((size_t)img * PX + (size_t)(2 * y) * 42 + x2) * 16 + q4;
    ushort4 r0 = ((const ushort4*)in)[base];
    ushort4 r1 = ((const ushort4*)in)[base + 42 * 16];
    unsigned short a0[4] = {r0.x, r0.y, r0.z, r0.w};
    unsigned short a1[4] = {r1.x, r1.y, r1.z, r1.w};
    ushort4 o;
    unsigned short* os = (unsigned short*)&o;
    #pragma unroll
    for (int k = 0; k < 4; ++k) {
        int c = q4 * 4 + k;
        float v = fmaxf(bits2f(a0[k]), bits2f(a1[k]));
        v = fmaf(v, ms[(g * 64 + c) * 2], ms[(g * 64 + c) * 2 + 1]);
        v = fmaxf(v, SLOPE * v);
        os[k] = bf16bits(v);
    }
    ((ushort4*)out)[i] = o;
}

// ---------------- MFMA conv 64->64; staging: bf16 raw OR fp32+BN+LReLU (fused bnact) -------
template <int S, int MBLK, bool BNIN, typename OT>
__global__ __launch_bounds__(256) void conv64m_k(const void* __restrict__ inv,
                                                 const unsigned short* __restrict__ wpk,
                                                 OT* __restrict__ out,
                                                 float* __restrict__ sums,
                                                 const float* __restrict__ msin)
{
    constexpr int P = S * S;
    constexpr int MT = MBLK / 64;
    constexpr int NB = (P + MBLK - 1) / MBLK;
    constexpr int SPAN = MBLK + 2 * S + 2;
    __shared__ __align__(16) unsigned short ls[SPAN * 72];
    __shared__ float qs[4][64], qs2[4][64];
    int img = blockIdx.x / NB;
    int p0 = (blockIdx.x % NB) * MBLK;
    int tid = threadIdx.x;
    int lane = tid & 63, wv = tid >> 6;
    int col = lane & 15, quad = lane >> 4;
    int g = (img < NQ) ? 0 : 1 + (img - NQ) / SHOT;
    if constexpr (!BNIN) {
        const unsigned short* ib = (const unsigned short*)inv + (size_t)img * P * 64;
        for (int u = tid; u < SPAN * 8; u += 256) {
            int pix = u >> 3, part = u & 7;
            int p = p0 - S - 1 + pix;
            short8 v = {0, 0, 0, 0, 0, 0, 0, 0};
            if (p >= 0 && p < P) v = *(const short8*)(ib + (size_t)p * 64 + part * 8);
            *(short8*)(ls + pix * 72 + part * 8) = v;
        }
    } else {
        const float* ib = (const float*)inv + (size_t)img * P * 64;
        int part = tid & 7;
        float ba[8], bb[8];
        #pragma unroll
        for (int j = 0; j < 8; ++j) {
            float2 ab = ((const float2*)msin)[g * 64 + part * 8 + j];
            ba[j] = ab.x;
            bb[j] = ab.y;
        }
        for (int u = tid; u < SPAN * 8; u += 256) {
            int pix = u >> 3;
            int p = p0 - S - 1 + pix;
            union { unsigned short us[8]; short8 s8; } o;
            #pragma unroll
            for (int j = 0; j < 8; ++j) o.us[j] = 0;
            if (p >= 0 && p < P) {
                const float* src = ib + (size_t)p * 64 + part * 8;
                float4 x0 = *(const float4*)src;
                float4 x1 = *(const float4*)(src + 4);
                float xs[8] = {x0.x, x0.y, x0.z, x0.w, x1.x, x1.y, x1.z, x1.w};
                #pragma unroll
                for (int j = 0; j < 8; ++j) {
                    float v = fmaf(xs[j], ba[j], bb[j]);
                    v = fmaxf(v, SLOPE * v);       // LeakyReLU
                    o.us[j] = bf16bits(v);
                }
            }
            *(short8*)(ls + pix * 72 + part * 8) = o.s8;
        }
    }
    __syncthreads();
    f32x4 acc[MT][4];
    #pragma unroll
    for (int mt = 0; mt < MT; ++mt)
        #pragma unroll
        for (int nt = 0; nt < 4; ++nt) acc[mt][nt] = (f32x4){0.f, 0.f, 0.f, 0.f};
    bool mok0[MT], mok2[MT];
    #pragma unroll
    for (int mt = 0; mt < MT; ++mt) {
        int xm = (p0 + wv * (MT * 16) + mt * 16 + col) % S;
        mok0[mt] = xm >= 1;
        mok2[mt] = xm <= S - 2;
    }
    const short8* wb = (const short8*)wpk;
    #pragma unroll
    for (int ky = 0; ky < 3; ++ky) {
        #pragma unroll
        for (int kx = 0; kx < 3; ++kx) {
            int t = ky * 3 + kx;
            int d = (ky - 1) * S + (kx - 1);
            #pragma unroll
            for (int half = 0; half < 2; ++half) {
                short8 b[4];
                #pragma unroll
                for (int nt = 0; nt < 4; ++nt)
                    b[nt] = wb[((t * 2 + half) * 4 + nt) * 64 + lane];
                #pragma unroll
                for (int mt = 0; mt < MT; ++mt) {
                    int idx = wv * (MT * 16) + mt * 16 + col + S + 1 + d;
                    short8 a = *(const short8*)(ls + idx * 72 + half * 32 + quad * 8);
                    bool ok = (kx == 0) ? mok0[mt] : (kx == 2) ? mok2[mt] : true;
                    if (!ok) a = (short8){0, 0, 0, 0, 0, 0, 0, 0};
                    #pragma unroll
                    for (int nt = 0; nt < 4; ++nt)
                        acc[mt][nt] = __builtin_amdgcn_mfma_f32_16x16x32_bf16(a, b[nt], acc[mt][nt], 0, 0, 0);
                }
            }
        }
    }
    float s[4] = {0.f, 0.f, 0.f, 0.f}, s2[4] = {0.f, 0.f, 0.f, 0.f};
    OT* ob = out + (size_t)img * P * 64;
    #pragma unroll
    for (int mt = 0; mt < MT; ++mt) {
        int tb = p0 + wv * (MT * 16) + mt * 16 + quad * 4;
        #pragma unroll
        for (int reg = 0; reg < 4; ++reg) {
            int pr = tb + reg;
            if (pr < P) {
                #pragma unroll
                for (int nt = 0; nt < 4; ++nt) {
                    float v = acc[mt][nt][reg];
                    stf(ob + (size_t)pr * 64 + nt * 16 + col, v);
                    s[nt] += v;
                    s2[nt] = fmaf(v, v, s2[nt]);
                }
            }
        }
    }
    #pragma unroll
    for (int d = 16; d < 64; d <<= 1)
        #pragma unroll
        for (int nt = 0; nt < 4; ++nt) {
            s[nt] += __shfl_xor(s[nt], d, 64);
            s2[nt] += __shfl_xor(s2[nt], d, 64);
        }
    if (quad == 0) {
        #pragma unroll
        for (int nt = 0; nt < 4; ++nt) {
            qs[wv][nt * 16 + col] = s[nt];
            qs2[wv][nt * 16 + col] = s2[nt];
        }
    }
    __syncthreads();
    if (wv == 0) {
        int rep = blockIdx.x & (NREP - 1);
        float ts = qs[0][lane] + qs[1][lane] + qs[2][lane] + qs[3][lane];
        float ts2 = qs2[0][lane] + qs2[1][lane] + qs2[2][lane] + qs2[3][lane];
        float* base = sums + ((size_t)(g * 64 + lane) * 2) * NREP + rep;
        atomicAdd(base, ts);
        atomicAdd(base + NREP, ts2);
    }
}

// fold (mean, invstd, gamma, beta) -> (a, b): y = x*a + b   (sums has NREP replicas)
__global__ void finalize_k(const float* __restrict__ sums, float* __restrict__ ms,
                           const float* __restrict__ gamma, const float* __restrict__ beta, int P)
{
    int i = blockIdx.x * blockDim.x + threadIdx.x;
    if (i >= 6 * 64) return;
    int g = i >> 6, c = i & 63;
    const float* ps = sums + (size_t)i * 2 * NREP;
    float s = 0.f, s2 = 0.f;
    #pragma unroll
    for (int r = 0; r < NREP; ++r) { s += ps[r]; s2 += ps[NREP + r]; }
    float cnt = (float)((g == 0 ? NQ : SHOT) * P);
    float mean = s / cnt;
    float var = s2 / cnt - mean * mean;
    float a = rsqrtf(var + EPSB) * gamma[c];
    ms[i * 2] = a;
    ms[i * 2 + 1] = fmaf(-mean, a, beta[c]);
}

// ---------------- BN + LeakyReLU + 2x2 maxpool -> bf16 (stage 2) ----------------
template <typename T>
__global__ __launch_bounds__(256) void bnpool_k(const T* __restrict__ x, const float* __restrict__ ms,
                                                __hip_bfloat16* __restrict__ out, int Win)
{
    int Wout = Win >> 1, Pout = Wout * Wout;
    size_t idx = (size_t)blockIdx.x * 256 + threadIdx.x;
    size_t total = (size_t)NIMG * Pout * 64;
    if (idx >= total) return;
    int c = (int)(idx & 63);
    size_t t = idx >> 6;
    int p = (int)(t % Pout);
    int img = (int)(t / Pout);
    int y = p / Wout, xo = p - y * Wout;
    int g = (img < NQ) ? 0 : 1 + (img - NQ) / SHOT;
    float a = ms[(g * 64 + c) * 2], bb = ms[(g * 64 + c) * 2 + 1];
    const T* base = x + (((size_t)img * Win + 2 * y) * Win + 2 * xo) * 64 + c;
    float mx = -3.4e38f;
    #pragma unroll
    for (int dy = 0; dy < 2; ++dy)
        #pragma unroll
        for (int dx = 0; dx < 2; ++dx) {
            float v = ldf(base + ((size_t)dy * Win + dx) * 64);
            v = fmaf(v, a, bb);
            v = v >= 0.f ? v : SLOPE * v;
            mx = fmaxf(mx, v);
        }
    out[idx] = __float2bfloat16(mx);
}

// ---------------- BN4 + LeakyReLU + per-pixel L2-normalize -> bf16 ----------------
__global__ __launch_bounds__(256) void bnnorm_k(const float* __restrict__ x, const float* __restrict__ ms,
                                                __hip_bfloat16* __restrict__ out)
{
    int lane = threadIdx.x & 63, wvr = threadIdx.x >> 6;
    int pix = blockIdx.x * 4 + wvr;        // one wave per pixel
    if (pix >= NIMG * P3) return;
    int img = pix / P3;
    int g = (img < NQ) ? 0 : 1 + (img - NQ) / SHOT;
    float v = fmaf(x[(size_t)pix * 64 + lane], ms[(g * 64 + lane) * 2], ms[(g * 64 + lane) * 2 + 1]);
    v = v >= 0.f ? v : SLOPE * v;
    float ss = v * v;
    #pragma unroll
    for (int d = 32; d > 0; d >>= 1) ss += __shfl_xor(ss, d, 64);
    out[(size_t)pix * 64 + lane] = __float2bfloat16(v * rsqrtf(ss));
}

// ---------------- similarity: m-split blocks, 128-row chunks, partial top-3 + merge --------
__device__ __forceinline__ void ins3(float v, float& t0, float& t1, float& t2)
{
    float n1 = __builtin_amdgcn_fmed3f(v, t0, t1);
    float n2 = __builtin_amdgcn_fmed3f(v, t1, t2);
    t0 = fmaxf(t0, v);
    t1 = n1;
    t2 = n2;
}

// grid: bq(32) x n(5) x qb(7) x mr(4) = 4480 blocks; block: 64q (wave=16q) x 576-row m-range
__global__ __launch_bounds__(256, 6) void sim_part_k(const __hip_bfloat16* __restrict__ fhat,
                                                     float* __restrict__ part)
{
    __shared__ __align__(16) unsigned short sl[128 * SLS]; // 128 m-rows, SLS-ushort stride
    int t = blockIdx.x;
    int mr = t & 3;
    int qb = (t >> 2) % 7;
    int n = (t / 28) % NCLS;
    int bq = t / (28 * NCLS);
    int tid = threadIdx.x, lane = tid & 63, wv = tid >> 6;
    int col = lane & 15, quad = lane >> 4;
    int q = qb * 64 + wv * 16 + col;
    int qc = q < P3 ? q : P3 - 1;
    const unsigned short* qp = (const unsigned short*)fhat + ((size_t)bq * P3 + qc) * 64;
    short8 a0 = *(const short8*)(qp + quad * 8);
    short8 a1 = *(const short8*)(qp + 32 + quad * 8);
    const unsigned short* sp = (const unsigned short*)fhat + (size_t)(NQ + n * SHOT) * P3 * 64;
    int m_lo = mr * MSPAN;
    int m_cnt = MM - m_lo; if (m_cnt > MSPAN) m_cnt = MSPAN;
    int m_hi = m_lo + m_cnt;
    int nch = (m_cnt + 127) >> 7;
    float t0[4], t1[4], t2[4];
    #pragma unroll
    for (int r = 0; r < 4; ++r) { t0[r] = NEGINF; t1[r] = NEGINF; t2[r] = NEGINF; }
    int srow = tid >> 3, scc = (tid & 7) * 8;
    for (int c = 0; c < nch; ++c) {
        int m0 = m_lo + c * 128;
        __syncthreads();
        #pragma unroll
        for (int pass = 0; pass < 4; ++pass) {
            int row = srow + pass * 32;
            int m = m0 + row;
            short8 vv = {0, 0, 0, 0, 0, 0, 0, 0};
            if (m < MM) vv = *(const short8*)(sp + (size_t)m * 64 + scc);
            *(short8*)(sl + row * SLS + scc) = vv;
        }
        __syncthreads();
        const unsigned short* sr = sl + col * SLS + quad * 8;
        #pragma unroll
        for (int mt = 0; mt < 8; ++mt) {
            if (m0 + mt * 16 < m_hi) {          // wave-uniform tile guard (no cross-range dup)
                short8 b0 = *(const short8*)(sr);
                short8 b1 = *(const short8*)(sr + 32);
                f32x4 acc = {0.f, 0.f, 0.f, 0.f};
                acc = __builtin_amdgcn_mfma_f32_16x16x32_bf16(a0, b0, acc, 0, 0, 0);
                acc = __builtin_amdgcn_mfma_f32_16x16x32_bf16(a1, b1, acc, 0, 0, 0);
                #pragma unroll
                for (int r = 0; r < 4; ++r) ins3(acc[r], t0[r], t1[r], t2[r]);
            }
            sr += 16 * SLS;
        }
    }
    #pragma unroll
    for (int d = 1; d < 16; d <<= 1)
        #pragma unroll
        for (int r = 0; r < 4; ++r) {
            float u0 = __shfl_xor(t0[r], d, 64);
            float u1 = __shfl_xor(t1[r], d, 64);
            float u2 = __shfl_xor(t2[r], d, 64);
            ins3(u0, t0[r], t1[r], t2[r]);
            ins3(u1, t0[r], t1[r], t2[r]);
            ins3(u2, t0[r], t1[r], t2[r]);
        }
    if (col == 0) {
        #pragma unroll
        for (int r = 0; r < 4; ++r) {
            int ql = wv * 16 + quad * 4 + r;
            float* pp = part + ((((size_t)(bq * NCLS + n) * 7 + qb) * 4 + mr) * 64 + ql) * 3;
            pp[0] = t0[r];
            pp[1] = t1[r];
            pp[2] = t2[r];
        }
    }
}

// one block per (bq, n): merge 4 m-range partials per q, sum top-3, write out directly
__global__ __launch_bounds__(256) void sim_merge_k(const float* __restrict__ part,
                                                   float* __restrict__ out)
{
    __shared__ float red[4];
    int b = blockIdx.x;                    // bq*NCLS + n
    int tid = threadIdx.x, lane = tid & 63, wv = tid >> 6;
    float s = 0.f;
    for (int q = tid; q < P3; q += 256) {
        int qb = q >> 6, ql = q & 63;
        const float* pp = part + (((size_t)b * 7 + qb) * 4 * 64 + ql) * 3;
        float v0 = pp[0], v1 = pp[1], v2 = pp[2];
        #pragma unroll
        for (int mr = 1; mr < 4; ++mr) {
            const float* pm = pp + (size_t)mr * 192;
            ins3(pm[0], v0, v1, v2);
            ins3(pm[1], v0, v1, v2);
            ins3(pm[2], v0, v1, v2);
        }
        s += v0 + v1 + v2;
    }
    #pragma unroll
    for (int d = 32; d > 0; d >>= 1) s += __shfl_xor(s, d, 64);
    if (lane == 0) red[wv] = s;
    __syncthreads();
    if (tid == 0) out[b] = red[0] + red[1] + red[2] + red[3];
}

extern "C" void kernel_launch(void* const* d_in, const int* in_sizes, int n_in,
                              void* d_out, int out_size, void* d_ws, size_t ws_size,
                              hipStream_t stream)
{
    const float* input1 = (const float*)d_in[0];
    const float* input2 = (const float*)d_in[1];
    const float* w1 = (const float*)d_in[2];
    const float* g1 = (const float*)d_in[3];
    const float* b1 = (const float*)d_in[4];
    const float* w2 = (const float*)d_in[5];
    const float* g2 = (const float*)d_in[6];
    const float* b2 = (const float*)d_in[7];
    const float* w3 = (const float*)d_in[8];
    const float* g3 = (const float*)d_in[9];
    const float* b3 = (const float*)d_in[10];
    const float* w4 = (const float*)d_in[11];
    const float* g4 = (const float*)d_in[12];
    const float* b4 = (const float*)d_in[13];
    float* out = (float*)d_out;

    char* w8 = (char*)d_ws;
    const size_t oB = 51480576;
    const size_t oT = oB + 12870144;
    const size_t STG = 6 * 64 * 2 * NREP * sizeof(float);   // 98304 B per stage
    __hip_bfloat16* xpool = (__hip_bfloat16*)(w8 + 0);      // [57][3528][64] bf16 25.7MB
    __hip_bfloat16* conv2raw = (__hip_bfloat16*)(w8 + 0);   // reuse A (12.87MB)
    float* conv3raw = (float*)(w8 + 0);                     // reuse A (6.43MB fp32)
    float* conv4raw = (float*)(w8 + 9652608);               // 6.43MB fp32
    __hip_bfloat16* fhat = (__hip_bfloat16*)(w8 + 16087680);
    __hip_bfloat16* pooled1 = (__hip_bfloat16*)(w8 + oB);   // 12.87MB
    __hip_bfloat16* pooled2 = (__hip_bfloat16*)(w8 + oB);   // reuse (3.2MB)
    float* sums = (float*)(w8 + oT);                        // 4 stages x 98304 B
    float* ms = (float*)(w8 + oT + 4 * STG);
    unsigned short* wpk2 = (unsigned short*)(w8 + oT + 4 * STG + 12288);
    unsigned short* wpk3 = (unsigned short*)(w8 + oT + 4 * STG + 12288 + 73728);
    unsigned short* wpk4 = (unsigned short*)(w8 + oT + 4 * STG + 12288 + 147456);
    unsigned short* wpk1 = (unsigned short*)(w8 + oT + 4 * STG + 12288 + 221184);
    const size_t oP = oT + 4 * STG + 12288 + 221184 + 8192;
    float* part = (float*)(w8 + oP);                        // 32*5*7*4*64*3 f32 = 3.44MB
    if (ws_size < oP + (size_t)NQ * NCLS * 7 * MRNG * 64 * 3 * sizeof(float)) return;
    float* sums1 = sums;
    float* sums2 = sums + 6 * 64 * 2 * NREP;
    float* sums3 = sums2 + 6 * 64 * 2 * NREP;
    float* sums4 = sums3 + 6 * 64 * 2 * NREP;

    // pack weights + zero stats (no memsets needed; sim_merge overwrites all of d_out)
    pack_all_k<<<448, 256, 0, stream>>>(w1, w2, w3, w4, wpk1, wpk2, wpk3, wpk4, sums);

    // stage 1: conv1 MFMA + in-register x-pool (+stats) -> finalize -> y-pool+BN+LReLU
    conv1m_k<<<NIMG * 28, 256, 0, stream>>>(input1, input2, wpk1, xpool, sums1);
    finalize_k<<<2, 256, 0, stream>>>(sums1, ms + 0, g1, b1, P1);
    bnpooly_k<<<(NIMG * P2 * 16 + 255) / 256, 256, 0, stream>>>(
        (const unsigned short*)xpool, ms + 0, (unsigned short*)pooled1);
    // stage 2: conv2 MFMA MBLK=128 (798 blocks) (+stats, bf16 out) -> finalize -> pool
    conv64m_k<42, 128, false, __hip_bfloat16><<<NIMG * 14, 256, 0, stream>>>(
        pooled1, wpk2, conv2raw, sums2, nullptr);
    finalize_k<<<2, 256, 0, stream>>>(sums2, ms + 768, g2, b2, P2);
    bnpool_k<__hip_bfloat16><<<6285, 256, 0, stream>>>(conv2raw, ms + 768, pooled2, 42);
    // stage 3: conv3 MFMA MBLK=64 (399 blocks) (+stats) -> finalize
    conv64m_k<21, 64, false, float><<<NIMG * 7, 256, 0, stream>>>(
        pooled2, wpk3, conv3raw, sums3, nullptr);
    finalize_k<<<2, 256, 0, stream>>>(sums3, ms + 1536, g3, b3, P3);
    // stage 4: conv4 MFMA MBLK=64 with BN3+LReLU fused staging (+stats) -> finalize -> norm
    conv64m_k<21, 64, true, float><<<NIMG * 7, 256, 0, stream>>>(
        conv3raw, wpk4, conv4raw, sums4, ms + 1536);
    finalize_k<<<2, 256, 0, stream>>>(sums4, ms + 2304, g4, b4, P3);
    bnnorm_k<<<6285, 256, 0, stream>>>(conv4raw, ms + 2304, fhat);
    // similarity: partial top-3 over m-ranges, then merge (writes d_out directly)
    sim_part_k<<<NQ * NCLS * 7 * MRNG, 256, 0, stream>>>(fhat, part);
    sim_merge_k<<<NQ * NCLS, 256, 0, stream>>>(part, out);
}

// Round 16
// 231.351 us; speedup vs baseline: 1.0423x; 1.0423x over previous
//
#include <hip/hip_runtime.h>
#include <hip/hip_bf16.h>
#include <stdint.h>

#define NQ 32
#define NCLS 5
#define SHOT 5
#define NIMG 57          // 32 query + 25 support
#define P1 7056          // 84*84
#define P2 1764          // 42*42
#define P3 441           // 21*21
#define PX 3528          // x-pooled stage-1 grid: 84 rows x 42
#define MM (SHOT*P3)     // 2205
#define EPSB 1e-5f
#define SLOPE 0.2f
#define NEGINF -3.4e38f
#define NREP 32          // stats atomic replication factor
#define MSPAN 576        // sim m-range rows per block (36 tiles)
#define MRNG 4           // m-ranges (4*576 >= 2205)
#define SLS 88           // sim LDS row stride in ushorts

typedef __attribute__((ext_vector_type(8))) short short8;
typedef __attribute__((ext_vector_type(4))) float f32x4;

__device__ __forceinline__ unsigned short bf16bits(float v)
{
    __hip_bfloat16 h = __float2bfloat16(v);
    return *reinterpret_cast<unsigned short*>(&h);
}
__device__ __forceinline__ float bits2f(unsigned short u)
{
    unsigned int x = ((unsigned int)u) << 16;
    return *reinterpret_cast<float*>(&x);
}

// ---------------- all weight packs + zero stats sums, one launch ----------------
__global__ void pack_all_k(const float* __restrict__ w1, const float* __restrict__ w2,
                           const float* __restrict__ w3, const float* __restrict__ w4,
                           unsigned short* __restrict__ wpk1, unsigned short* __restrict__ wpk2,
                           unsigned short* __restrict__ wpk3, unsigned short* __restrict__ wpk4,
                           float* __restrict__ sums)
{
    int i = blockIdx.x * 256 + threadIdx.x;
    if (i < 4 * 6 * 64 * 2 * NREP) sums[i] = 0.f;   // zero all 4 stages' stat sums
    if (i < 3 * 36864) {
        int set = i / 36864, ii = i - set * 36864;
        const float* w = (set == 0) ? w2 : (set == 1) ? w3 : w4;
        unsigned short* wpk = (set == 0) ? wpk2 : (set == 1) ? wpk3 : wpk4;
        int j = ii & 7, lane = (ii >> 3) & 63, chunk = ii >> 9;
        int nt = chunk & 3, half = (chunk >> 2) & 1, t = chunk >> 3;
        int co = nt * 16 + (lane & 15);
        int ci = half * 32 + (lane >> 4) * 8 + j;
        wpk[ii] = bf16bits(w[co * 576 + ci * 9 + t]);
    } else {
        int ii = i - 3 * 36864;
        if (ii >= 4096) return;
        int j = ii & 7, lane = (ii >> 3) & 63, c8 = ii >> 9;
        int nt = c8 & 3, f = c8 >> 2;
        int co = nt * 16 + (lane & 15), q = lane >> 4;
        int k = q * 8 + j;
        float val = 0.f;
        if (f == 0) {
            int t = k >> 2, ci = k & 3;
            if (ci < 3) val = w1[co * 27 + ci * 9 + t];
        } else if (k < 4) {
            int ci = k & 3;
            if (ci < 3) val = w1[co * 27 + ci * 9 + 8];
        }
        wpk1[ii] = bf16bits(val);
    }
}

// ---------------- MFMA conv1 3->64, fused BN stats + in-register x-pair max ----------------
__global__ __launch_bounds__(256) void conv1m_k(const float* __restrict__ in1,
                                                const float* __restrict__ in2,
                                                const unsigned short* __restrict__ wpk1,
                                                __hip_bfloat16* __restrict__ xpool,
                                                float* __restrict__ sums)
{
    constexpr int S = 84, P = P1, MBLK = 256, NB = 28, SPAN = MBLK + 2 * S + 2;  // 426
    __shared__ __align__(16) unsigned short ls4[SPAN * 4];   // 8 B per pixel [c0,c1,c2,0]
    __shared__ float qs[4][64], qs2[4][64];
    int img = blockIdx.x / NB;
    int p0 = (blockIdx.x % NB) * MBLK;
    int tid = threadIdx.x, lane = tid & 63, wv = tid >> 6;
    int col = lane & 15, quad = lane >> 4;
    const float* in = (img < NQ) ? in1 + (size_t)img * 3 * P1
                                 : in2 + (size_t)(img - NQ) * 3 * P1;
    for (int u = tid; u < SPAN; u += 256) {
        int p = p0 - S - 1 + u;
        union { unsigned short us[4]; uint2 u2; } o;
        o.u2 = (uint2){0u, 0u};
        if (p >= 0 && p < P) {
            o.us[0] = bf16bits(in[p]);
            o.us[1] = bf16bits(in[P1 + p]);
            o.us[2] = bf16bits(in[2 * P1 + p]);
        }
        *(uint2*)(ls4 + u * 4) = o.u2;
    }
    const short8* wb = (const short8*)wpk1;
    short8 b0[4], b1[4];
    #pragma unroll
    for (int nt = 0; nt < 4; ++nt) {
        b0[nt] = wb[(size_t)(nt * 64 + lane)];
        b1[nt] = wb[(size_t)((4 + nt) * 64 + lane)];
    }
    int t0 = 2 * quad, t1 = t0 + 1;
    int d0 = (t0 / 3 - 1) * S + (t0 % 3 - 1);
    int d1 = (t1 / 3 - 1) * S + (t1 % 3 - 1);
    const int d8 = S + 1;
    int tx0 = t0 % 3, tx1 = t1 % 3;
    __syncthreads();
    f32x4 acc[4][4];
    #pragma unroll
    for (int mt = 0; mt < 4; ++mt)
        #pragma unroll
        for (int nt = 0; nt < 4; ++nt) acc[mt][nt] = (f32x4){0.f, 0.f, 0.f, 0.f};
    #pragma unroll
    for (int mt = 0; mt < 4; ++mt) {
        int pl = wv * 64 + mt * 16 + col;
        int xm = (p0 + pl) % S;
        int base = pl + S + 1;
        uint2 h0 = *(const uint2*)(ls4 + (base + d0) * 4);
        uint2 h1 = *(const uint2*)(ls4 + (base + d1) * 4);
        uint2 h8 = *(const uint2*)(ls4 + (base + d8) * 4);
        bool ok0 = (tx0 == 0) ? (xm >= 1) : ((tx0 == 2) ? (xm <= S - 2) : true);
        bool ok1 = (tx1 == 0) ? (xm >= 1) : ((tx1 == 2) ? (xm <= S - 2) : true);
        bool ok8 = (quad == 0) && (xm <= S - 2);
        if (!ok0) h0 = (uint2){0u, 0u};
        if (!ok1) h1 = (uint2){0u, 0u};
        if (!ok8) h8 = (uint2){0u, 0u};
        union { uint4 u; short8 s; } ca, cb;
        ca.u = (uint4){h0.x, h0.y, h1.x, h1.y};
        cb.u = (uint4){h8.x, h8.y, 0u, 0u};
        #pragma unroll
        for (int nt = 0; nt < 4; ++nt) {
            acc[mt][nt] = __builtin_amdgcn_mfma_f32_16x16x32_bf16(ca.s, b0[nt], acc[mt][nt], 0, 0, 0);
            acc[mt][nt] = __builtin_amdgcn_mfma_f32_16x16x32_bf16(cb.s, b1[nt], acc[mt][nt], 0, 0, 0);
        }
    }
    float s[4] = {0.f, 0.f, 0.f, 0.f}, s2[4] = {0.f, 0.f, 0.f, 0.f};
    __hip_bfloat16* ob = xpool + (size_t)img * PX * 64;
    #pragma unroll
    for (int mt = 0; mt < 4; ++mt) {
        int tb = p0 + wv * 64 + mt * 16 + quad * 4;
        #pragma unroll
        for (int reg = 0; reg < 4; ++reg) {
            int pr = tb + reg;
            if (pr < P) {
                #pragma unroll
                for (int nt = 0; nt < 4; ++nt) {
                    float v = acc[mt][nt][reg];
                    s[nt] += v;
                    s2[nt] = fmaf(v, v, s2[nt]);
                }
            }
        }
        #pragma unroll
        for (int pr2 = 0; pr2 < 2; ++pr2) {
            int m0 = tb + pr2 * 2;
            if (m0 < P) {
                #pragma unroll
                for (int nt = 0; nt < 4; ++nt) {
                    float v = fmaxf(acc[mt][nt][pr2 * 2], acc[mt][nt][pr2 * 2 + 1]);
                    ob[(size_t)(m0 >> 1) * 64 + nt * 16 + col] = __float2bfloat16(v);
                }
            }
        }
    }
    #pragma unroll
    for (int d = 16; d < 64; d <<= 1)
        #pragma unroll
        for (int nt = 0; nt < 4; ++nt) {
            s[nt] += __shfl_xor(s[nt], d, 64);
            s2[nt] += __shfl_xor(s2[nt], d, 64);
        }
    if (quad == 0) {
        #pragma unroll
        for (int nt = 0; nt < 4; ++nt) {
            qs[wv][nt * 16 + col] = s[nt];
            qs2[wv][nt * 16 + col] = s2[nt];
        }
    }
    __syncthreads();
    if (wv == 0) {
        int g = (img < NQ) ? 0 : 1 + (img - NQ) / SHOT;
        int rep = blockIdx.x & (NREP - 1);
        float ts = qs[0][lane] + qs[1][lane] + qs[2][lane] + qs[3][lane];
        float ts2 = qs2[0][lane] + qs2[1][lane] + qs2[2][lane] + qs2[3][lane];
        float* base = sums + ((size_t)(g * 64 + lane) * 2) * NREP + rep;
        atomicAdd(base, ts);
        atomicAdd(base + NREP, ts2);
    }
}

// ---------- y-pair max + BN + LeakyReLU on x-pooled raw [2W x W] -> [W x W] bf16 ----------
template <int W>
__global__ __launch_bounds__(256) void bnpooly_k(const unsigned short* __restrict__ in,
                                                 const float* __restrict__ ms,
                                                 unsigned short* __restrict__ out)
{
    constexpr int POUT = W * W;
    int i = blockIdx.x * 256 + threadIdx.x;
    if (i >= NIMG * POUT * 16) return;     // ushort4 groups
    int q4 = i & 15;
    int t = i >> 4;
    int p = t % POUT;
    int img = t / POUT;
    int y = p / W, x2 = p - y * W;
    int g = (img < NQ) ? 0 : 1 + (img - NQ) / SHOT;
    size_t base = ((size_t)img * (2 * POUT) + (size_t)(2 * y) * W + x2) * 16 + q4;
    ushort4 r0 = ((const ushort4*)in)[base];
    ushort4 r1 = ((const ushort4*)in)[base + W * 16];
    unsigned short a0[4] = {r0.x, r0.y, r0.z, r0.w};
    unsigned short a1[4] = {r1.x, r1.y, r1.z, r1.w};
    ushort4 o;
    unsigned short* os = (unsigned short*)&o;
    #pragma unroll
    for (int k = 0; k < 4; ++k) {
        int c = q4 * 4 + k;
        float v = fmaxf(bits2f(a0[k]), bits2f(a1[k]));
        v = fmaf(v, ms[(g * 64 + c) * 2], ms[(g * 64 + c) * 2 + 1]);
        v = fmaxf(v, SLOPE * v);
        os[k] = bf16bits(v);
    }
    ((ushort4*)out)[i] = o;
}

// ------- MFMA conv 64->64; staging bf16 raw OR bf16+BN+LReLU; out raw bf16 (opt x-pool) ----
template <int S, int MBLK, bool BNIN, bool POOLX>
__global__ __launch_bounds__(256) void conv64m_k(const unsigned short* __restrict__ inv,
                                                 const unsigned short* __restrict__ wpk,
                                                 __hip_bfloat16* __restrict__ out,
                                                 float* __restrict__ sums,
                                                 const float* __restrict__ msin)
{
    constexpr int P = S * S;
    constexpr int MT = MBLK / 64;
    constexpr int NB = (P + MBLK - 1) / MBLK;
    constexpr int SPAN = MBLK + 2 * S + 2;
    __shared__ __align__(16) unsigned short ls[SPAN * 72];
    __shared__ float qs[4][64], qs2[4][64];
    int img = blockIdx.x / NB;
    int p0 = (blockIdx.x % NB) * MBLK;
    int tid = threadIdx.x;
    int lane = tid & 63, wv = tid >> 6;
    int col = lane & 15, quad = lane >> 4;
    int g = (img < NQ) ? 0 : 1 + (img - NQ) / SHOT;
    const unsigned short* ib = inv + (size_t)img * P * 64;
    if constexpr (!BNIN) {
        for (int u = tid; u < SPAN * 8; u += 256) {
            int pix = u >> 3, part = u & 7;
            int p = p0 - S - 1 + pix;
            short8 v = {0, 0, 0, 0, 0, 0, 0, 0};
            if (p >= 0 && p < P) v = *(const short8*)(ib + (size_t)p * 64 + part * 8);
            *(short8*)(ls + pix * 72 + part * 8) = v;
        }
    } else {
        // fused BN+LReLU on bf16 raw input during staging (part = tid&7 loop-invariant)
        int part = tid & 7;
        float ba[8], bb[8];
        #pragma unroll
        for (int j = 0; j < 8; ++j) {
            float2 ab = ((const float2*)msin)[g * 64 + part * 8 + j];
            ba[j] = ab.x;
            bb[j] = ab.y;
        }
        for (int u = tid; u < SPAN * 8; u += 256) {
            int pix = u >> 3;
            int p = p0 - S - 1 + pix;
            union { unsigned short us[8]; short8 s8; } o;
            #pragma unroll
            for (int j = 0; j < 8; ++j) o.us[j] = 0;
            if (p >= 0 && p < P) {
                union { short8 s8; unsigned short us[8]; } x;
                x.s8 = *(const short8*)(ib + (size_t)p * 64 + part * 8);
                #pragma unroll
                for (int j = 0; j < 8; ++j) {
                    float v = fmaf(bits2f(x.us[j]), ba[j], bb[j]);
                    v = fmaxf(v, SLOPE * v);       // LeakyReLU
                    o.us[j] = bf16bits(v);
                }
            }
            *(short8*)(ls + pix * 72 + part * 8) = o.s8;
        }
    }
    __syncthreads();
    f32x4 acc[MT][4];
    #pragma unroll
    for (int mt = 0; mt < MT; ++mt)
        #pragma unroll
        for (int nt = 0; nt < 4; ++nt) acc[mt][nt] = (f32x4){0.f, 0.f, 0.f, 0.f};
    bool mok0[MT], mok2[MT];
    #pragma unroll
    for (int mt = 0; mt < MT; ++mt) {
        int xm = (p0 + wv * (MT * 16) + mt * 16 + col) % S;
        mok0[mt] = xm >= 1;
        mok2[mt] = xm <= S - 2;
    }
    const short8* wb = (const short8*)wpk;
    #pragma unroll
    for (int ky = 0; ky < 3; ++ky) {
        #pragma unroll
        for (int kx = 0; kx < 3; ++kx) {
            int t = ky * 3 + kx;
            int d = (ky - 1) * S + (kx - 1);
            #pragma unroll
            for (int half = 0; half < 2; ++half) {
                short8 b[4];
                #pragma unroll
                for (int nt = 0; nt < 4; ++nt)
                    b[nt] = wb[((t * 2 + half) * 4 + nt) * 64 + lane];
                #pragma unroll
                for (int mt = 0; mt < MT; ++mt) {
                    int idx = wv * (MT * 16) + mt * 16 + col + S + 1 + d;
                    short8 a = *(const short8*)(ls + idx * 72 + half * 32 + quad * 8);
                    bool ok = (kx == 0) ? mok0[mt] : (kx == 2) ? mok2[mt] : true;
                    if (!ok) a = (short8){0, 0, 0, 0, 0, 0, 0, 0};
                    #pragma unroll
                    for (int nt = 0; nt < 4; ++nt)
                        acc[mt][nt] = __builtin_amdgcn_mfma_f32_16x16x32_bf16(a, b[nt], acc[mt][nt], 0, 0, 0);
                }
            }
        }
    }
    float s[4] = {0.f, 0.f, 0.f, 0.f}, s2[4] = {0.f, 0.f, 0.f, 0.f};
    __hip_bfloat16* ob = out + (size_t)img * (POOLX ? P / 2 : P) * 64;
    #pragma unroll
    for (int mt = 0; mt < MT; ++mt) {
        int tb = p0 + wv * (MT * 16) + mt * 16 + quad * 4;
        #pragma unroll
        for (int reg = 0; reg < 4; ++reg) {
            int pr = tb + reg;
            if (pr < P) {
                #pragma unroll
                for (int nt = 0; nt < 4; ++nt) {
                    float v = acc[mt][nt][reg];
                    s[nt] += v;
                    s2[nt] = fmaf(v, v, s2[nt]);
                }
            }
        }
        if constexpr (POOLX) {
            #pragma unroll
            for (int pr2 = 0; pr2 < 2; ++pr2) {
                int m0 = tb + pr2 * 2;
                if (m0 < P) {
                    #pragma unroll
                    for (int nt = 0; nt < 4; ++nt) {
                        float v = fmaxf(acc[mt][nt][pr2 * 2], acc[mt][nt][pr2 * 2 + 1]);
                        ob[(size_t)(m0 >> 1) * 64 + nt * 16 + col] = __float2bfloat16(v);
                    }
                }
            }
        } else {
            #pragma unroll
            for (int reg = 0; reg < 4; ++reg) {
                int pr = tb + reg;
                if (pr < P) {
                    #pragma unroll
                    for (int nt = 0; nt < 4; ++nt)
                        ob[(size_t)pr * 64 + nt * 16 + col] = __float2bfloat16(acc[mt][nt][reg]);
                }
            }
        }
    }
    #pragma unroll
    for (int d = 16; d < 64; d <<= 1)
        #pragma unroll
        for (int nt = 0; nt < 4; ++nt) {
            s[nt] += __shfl_xor(s[nt], d, 64);
            s2[nt] += __shfl_xor(s2[nt], d, 64);
        }
    if (quad == 0) {
        #pragma unroll
        for (int nt = 0; nt < 4; ++nt) {
            qs[wv][nt * 16 + col] = s[nt];
            qs2[wv][nt * 16 + col] = s2[nt];
        }
    }
    __syncthreads();
    if (wv == 0) {
        int rep = blockIdx.x & (NREP - 1);
        float ts = qs[0][lane] + qs[1][lane] + qs[2][lane] + qs[3][lane];
        float ts2 = qs2[0][lane] + qs2[1][lane] + qs2[2][lane] + qs2[3][lane];
        float* base = sums + ((size_t)(g * 64 + lane) * 2) * NREP + rep;
        atomicAdd(base, ts);
        atomicAdd(base + NREP, ts2);
    }
}

// fold (mean, invstd, gamma, beta) -> (a, b): y = x*a + b   (sums has NREP replicas)
__global__ void finalize_k(const float* __restrict__ sums, float* __restrict__ ms,
                           const float* __restrict__ gamma, const float* __restrict__ beta, int P)
{
    int i = blockIdx.x * blockDim.x + threadIdx.x;
    if (i >= 6 * 64) return;
    int g = i >> 6, c = i & 63;
    const float* ps = sums + (size_t)i * 2 * NREP;
    float s = 0.f, s2 = 0.f;
    #pragma unroll
    for (int r = 0; r < NREP; ++r) { s += ps[r]; s2 += ps[NREP + r]; }
    float cnt = (float)((g == 0 ? NQ : SHOT) * P);
    float mean = s / cnt;
    float var = s2 / cnt - mean * mean;
    float a = rsqrtf(var + EPSB) * gamma[c];
    ms[i * 2] = a;
    ms[i * 2 + 1] = fmaf(-mean, a, beta[c]);
}

// ---------------- BN4 + LeakyReLU + per-pixel L2-normalize on bf16 raw -> bf16 -------------
__global__ __launch_bounds__(256) void bnnorm_k(const unsigned short* __restrict__ x,
                                                const float* __restrict__ ms,
                                                __hip_bfloat16* __restrict__ out)
{
    int lane = threadIdx.x & 63, wvr = threadIdx.x >> 6;
    int pix = blockIdx.x * 4 + wvr;        // one wave per pixel
    if (pix >= NIMG * P3) return;
    int img = pix / P3;
    int g = (img < NQ) ? 0 : 1 + (img - NQ) / SHOT;
    float v = fmaf(bits2f(x[(size_t)pix * 64 + lane]), ms[(g * 64 + lane) * 2], ms[(g * 64 + lane) * 2 + 1]);
    v = v >= 0.f ? v : SLOPE * v;
    float ss = v * v;
    #pragma unroll
    for (int d = 32; d > 0; d >>= 1) ss += __shfl_xor(ss, d, 64);
    out[(size_t)pix * 64 + lane] = __float2bfloat16(v * rsqrtf(ss));
}

// ---------------- similarity: m-split blocks, 64-row chunks, partial top-3 + merge ---------
__device__ __forceinline__ void ins3(float v, float& t0, float& t1, float& t2)
{
    float n1 = __builtin_amdgcn_fmed3f(v, t0, t1);
    float n2 = __builtin_amdgcn_fmed3f(v, t1, t2);
    t0 = fmaxf(t0, v);
    t1 = n1;
    t2 = n2;
}

// grid: bq(32) x n(5) x qb(7) x mr(4) = 4480 blocks; block: 64q (wave=16q) x 576-row m-range
__global__ __launch_bounds__(256, 6) void sim_part_k(const __hip_bfloat16* __restrict__ fhat,
                                                     float* __restrict__ part)
{
    __shared__ __align__(16) unsigned short sl[64 * SLS];  // 64 m-rows, SLS-ushort stride
    int t = blockIdx.x;
    int mr = t & 3;
    int qb = (t >> 2) % 7;
    int n = (t / 28) % NCLS;
    int bq = t / (28 * NCLS);
    int tid = threadIdx.x, lane = tid & 63, wv = tid >> 6;
    int col = lane & 15, quad = lane >> 4;
    int q = qb * 64 + wv * 16 + col;
    int qc = q < P3 ? q : P3 - 1;
    const unsigned short* qp = (const unsigned short*)fhat + ((size_t)bq * P3 + qc) * 64;
    short8 a0 = *(const short8*)(qp + quad * 8);
    short8 a1 = *(const short8*)(qp + 32 + quad * 8);
    const unsigned short* sp = (const unsigned short*)fhat + (size_t)(NQ + n * SHOT) * P3 * 64;
    int m_lo = mr * MSPAN;
    int m_cnt = MM - m_lo; if (m_cnt > MSPAN) m_cnt = MSPAN;
    int nch = (m_cnt + 63) >> 6;
    float t0[4], t1[4], t2[4];
    #pragma unroll
    for (int r = 0; r < 4; ++r) { t0[r] = NEGINF; t1[r] = NEGINF; t2[r] = NEGINF; }
    int srow = tid >> 3, scc = (tid & 7) * 8;
    for (int c = 0; c < nch; ++c) {
        int m0 = m_lo + c * 64;
        __syncthreads();
        #pragma unroll
        for (int pass = 0; pass < 2; ++pass) {
            int row = srow + pass * 32;
            int m = m0 + row;
            short8 vv = {0, 0, 0, 0, 0, 0, 0, 0};
            if (m < MM) vv = *(const short8*)(sp + (size_t)m * 64 + scc);
            *(short8*)(sl + row * SLS + scc) = vv;
        }
        __syncthreads();
        const unsigned short* sr = sl + col * SLS + quad * 8;
        #pragma unroll
        for (int mt = 0; mt < 4; ++mt) {
            if (m0 + mt * 16 < MM) {            // wave-uniform: skip fully-fake tiles
                short8 b0 = *(const short8*)(sr);
                short8 b1 = *(const short8*)(sr + 32);
                f32x4 acc = {0.f, 0.f, 0.f, 0.f};
                acc = __builtin_amdgcn_mfma_f32_16x16x32_bf16(a0, b0, acc, 0, 0, 0);
                acc = __builtin_amdgcn_mfma_f32_16x16x32_bf16(a1, b1, acc, 0, 0, 0);
                #pragma unroll
                for (int r = 0; r < 4; ++r) ins3(acc[r], t0[r], t1[r], t2[r]);
            }
            sr += 16 * SLS;
        }
    }
    #pragma unroll
    for (int d = 1; d < 16; d <<= 1)
        #pragma unroll
        for (int r = 0; r < 4; ++r) {
            float u0 = __shfl_xor(t0[r], d, 64);
            float u1 = __shfl_xor(t1[r], d, 64);
            float u2 = __shfl_xor(t2[r], d, 64);
            ins3(u0, t0[r], t1[r], t2[r]);
            ins3(u1, t0[r], t1[r], t2[r]);
            ins3(u2, t0[r], t1[r], t2[r]);
        }
    if (col == 0) {
        #pragma unroll
        for (int r = 0; r < 4; ++r) {
            int ql = wv * 16 + quad * 4 + r;
            float* pp = part + ((((size_t)(bq * NCLS + n) * 7 + qb) * 4 + mr) * 64 + ql) * 3;
            pp[0] = t0[r];
            pp[1] = t1[r];
            pp[2] = t2[r];
        }
    }
}

// one block per (bq, n): merge 4 m-range partials per q, sum top-3, write out directly
__global__ __launch_bounds__(256) void sim_merge_k(const float* __restrict__ part,
                                                   float* __restrict__ out)
{
    __shared__ float red[4];
    int b = blockIdx.x;                    // bq*NCLS + n
    int tid = threadIdx.x, lane = tid & 63, wv = tid >> 6;
    float s = 0.f;
    for (int q = tid; q < P3; q += 256) {
        int qb = q >> 6, ql = q & 63;
        const float* pp = part + (((size_t)b * 7 + qb) * 4 * 64 + ql) * 3;
        float v0 = pp[0], v1 = pp[1], v2 = pp[2];
        #pragma unroll
        for (int mr = 1; mr < 4; ++mr) {
            const float* pm = pp + (size_t)mr * 192;
            ins3(pm[0], v0, v1, v2);
            ins3(pm[1], v0, v1, v2);
            ins3(pm[2], v0, v1, v2);
        }
        s += v0 + v1 + v2;
    }
    #pragma unroll
    for (int d = 32; d > 0; d >>= 1) s += __shfl_xor(s, d, 64);
    if (lane == 0) red[wv] = s;
    __syncthreads();
    if (tid == 0) out[b] = red[0] + red[1] + red[2] + red[3];
}

extern "C" void kernel_launch(void* const* d_in, const int* in_sizes, int n_in,
                              void* d_out, int out_size, void* d_ws, size_t ws_size,
                              hipStream_t stream)
{
    const float* input1 = (const float*)d_in[0];
    const float* input2 = (const float*)d_in[1];
    const float* w1 = (const float*)d_in[2];
    const float* g1 = (const float*)d_in[3];
    const float* b1 = (const float*)d_in[4];
    const float* w2 = (const float*)d_in[5];
    const float* g2 = (const float*)d_in[6];
    const float* b2 = (const float*)d_in[7];
    const float* w3 = (const float*)d_in[8];
    const float* g3 = (const float*)d_in[9];
    const float* b3 = (const float*)d_in[10];
    const float* w4 = (const float*)d_in[11];
    const float* g4 = (const float*)d_in[12];
    const float* b4 = (const float*)d_in[13];
    float* out = (float*)d_out;

    char* w8 = (char*)d_ws;
    const size_t oB = 51480576;
    const size_t oT = oB + 12870144;
    const size_t STG = 6 * 64 * 2 * NREP * sizeof(float);   // 98304 B per stage
    __hip_bfloat16* xpool = (__hip_bfloat16*)(w8 + 0);      // [57][3528][64] bf16 25.7MB
    __hip_bfloat16* xpool2 = (__hip_bfloat16*)(w8 + 0);     // reuse A: [57][882][64] bf16 6.44MB
    __hip_bfloat16* conv3raw = (__hip_bfloat16*)(w8 + 0);   // reuse A: [57][441][64] bf16 3.2MB
    __hip_bfloat16* conv4raw = (__hip_bfloat16*)(w8 + 9652608);  // 3.2MB bf16
    __hip_bfloat16* fhat = (__hip_bfloat16*)(w8 + 16087680);
    __hip_bfloat16* pooled1 = (__hip_bfloat16*)(w8 + oB);   // 12.87MB
    __hip_bfloat16* pooled2 = (__hip_bfloat16*)(w8 + oB);   // reuse (3.2MB)
    float* sums = (float*)(w8 + oT);                        // 4 stages x 98304 B
    float* ms = (float*)(w8 + oT + 4 * STG);
    unsigned short* wpk2 = (unsigned short*)(w8 + oT + 4 * STG + 12288);
    unsigned short* wpk3 = (unsigned short*)(w8 + oT + 4 * STG + 12288 + 73728);
    unsigned short* wpk4 = (unsigned short*)(w8 + oT + 4 * STG + 12288 + 147456);
    unsigned short* wpk1 = (unsigned short*)(w8 + oT + 4 * STG + 12288 + 221184);
    const size_t oP = oT + 4 * STG + 12288 + 221184 + 8192;
    float* part = (float*)(w8 + oP);                        // 32*5*7*4*64*3 f32 = 3.44MB
    if (ws_size < oP + (size_t)NQ * NCLS * 7 * MRNG * 64 * 3 * sizeof(float)) return;
    float* sums1 = sums;
    float* sums2 = sums + 6 * 64 * 2 * NREP;
    float* sums3 = sums2 + 6 * 64 * 2 * NREP;
    float* sums4 = sums3 + 6 * 64 * 2 * NREP;

    // pack weights + zero stats (no memsets needed; sim_merge overwrites all of d_out)
    pack_all_k<<<448, 256, 0, stream>>>(w1, w2, w3, w4, wpk1, wpk2, wpk3, wpk4, sums);

    // stage 1: conv1 MFMA + in-register x-pool (+stats) -> finalize -> y-pool+BN+LReLU
    conv1m_k<<<NIMG * 28, 256, 0, stream>>>(input1, input2, wpk1, xpool, sums1);
    finalize_k<<<2, 256, 0, stream>>>(sums1, ms + 0, g1, b1, P1);
    bnpooly_k<42><<<(NIMG * P2 * 16 + 255) / 256, 256, 0, stream>>>(
        (const unsigned short*)xpool, ms + 0, (unsigned short*)pooled1);
    // stage 2: conv2 MFMA MBLK=256 + in-register x-pool (+stats) -> finalize -> y-pool+BN
    conv64m_k<42, 256, false, true><<<NIMG * 7, 256, 0, stream>>>(
        (const unsigned short*)pooled1, wpk2, xpool2, sums2, nullptr);
    finalize_k<<<2, 256, 0, stream>>>(sums2, ms + 768, g2, b2, P2);
    bnpooly_k<21><<<(NIMG * P3 * 16 + 255) / 256, 256, 0, stream>>>(
        (const unsigned short*)xpool2, ms + 768, (unsigned short*)pooled2);
    // stage 3: conv3 MFMA MBLK=128 (+stats, bf16 raw out) -> finalize
    conv64m_k<21, 128, false, false><<<NIMG * 4, 256, 0, stream>>>(
        (const unsigned short*)pooled2, wpk3, conv3raw, sums3, nullptr);
    finalize_k<<<2, 256, 0, stream>>>(sums3, ms + 1536, g3, b3, P3);
    // stage 4: conv4 MFMA MBLK=128, BN3+LReLU fused in staging (+stats, bf16 raw out)
    conv64m_k<21, 128, true, false><<<NIMG * 4, 256, 0, stream>>>(
        (const unsigned short*)conv3raw, wpk4, conv4raw, sums4, ms + 1536);
    finalize_k<<<2, 256, 0, stream>>>(sums4, ms + 2304, g4, b4, P3);
    bnnorm_k<<<6285, 256, 0, stream>>>((const unsigned short*)conv4raw, ms + 2304, fhat);
    // similarity: partial top-3 over m-ranges, then merge (writes d_out directly)
    sim_part_k<<<NQ * NCLS * 7 * MRNG, 256, 0, stream>>>(fhat, part);
    sim_merge_k<<<NQ * NCLS, 256, 0, stream>>>(part, out);
}

// Round 17
// 222.468 us; speedup vs baseline: 1.0839x; 1.0399x over previous
//
#include <hip/hip_runtime.h>
#include <hip/hip_bf16.h>
#include <stdint.h>

#define NQ 32
#define NCLS 5
#define SHOT 5
#define NIMG 57          // 32 query + 25 support
#define P1 7056          // 84*84
#define P2 1764          // 42*42
#define P3 441           // 21*21
#define PX 3528          // x-pooled stage-1 grid: 84 rows x 42
#define MM (SHOT*P3)     // 2205
#define EPSB 1e-5f
#define SLOPE 0.2f
#define NEGINF -3.4e38f
#define NREP 32          // stats atomic replication factor
#define MSPAN 576        // sim m-range rows per block (36 tiles)
#define MRNG 4           // m-ranges (4*576 >= 2205)
#define SLS 88           // sim LDS row stride in ushorts

typedef __attribute__((ext_vector_type(8))) short short8;
typedef __attribute__((ext_vector_type(4))) float f32x4;

__device__ __forceinline__ unsigned short bf16bits(float v)
{
    __hip_bfloat16 h = __float2bfloat16(v);
    return *reinterpret_cast<unsigned short*>(&h);
}
__device__ __forceinline__ float bits2f(unsigned short u)
{
    unsigned int x = ((unsigned int)u) << 16;
    return *reinterpret_cast<float*>(&x);
}

// ---------------- all weight packs + zero stats sums, one launch ----------------
__global__ void pack_all_k(const float* __restrict__ w1, const float* __restrict__ w2,
                           const float* __restrict__ w3, const float* __restrict__ w4,
                           unsigned short* __restrict__ wpk1, unsigned short* __restrict__ wpk2,
                           unsigned short* __restrict__ wpk3, unsigned short* __restrict__ wpk4,
                           float* __restrict__ sums)
{
    int i = blockIdx.x * 256 + threadIdx.x;
    if (i < 4 * 6 * 64 * 2 * NREP) sums[i] = 0.f;   // zero all 4 stages' stat sums
    if (i < 3 * 36864) {
        int set = i / 36864, ii = i - set * 36864;
        const float* w = (set == 0) ? w2 : (set == 1) ? w3 : w4;
        unsigned short* wpk = (set == 0) ? wpk2 : (set == 1) ? wpk3 : wpk4;
        int j = ii & 7, lane = (ii >> 3) & 63, chunk = ii >> 9;
        int nt = chunk & 3, half = (chunk >> 2) & 1, t = chunk >> 3;
        int co = nt * 16 + (lane & 15);
        int ci = half * 32 + (lane >> 4) * 8 + j;
        wpk[ii] = bf16bits(w[co * 576 + ci * 9 + t]);
    } else {
        int ii = i - 3 * 36864;
        if (ii >= 4096) return;
        int j = ii & 7, lane = (ii >> 3) & 63, c8 = ii >> 9;
        int nt = c8 & 3, f = c8 >> 2;
        int co = nt * 16 + (lane & 15), q = lane >> 4;
        int k = q * 8 + j;
        float val = 0.f;
        if (f == 0) {
            int t = k >> 2, ci = k & 3;
            if (ci < 3) val = w1[co * 27 + ci * 9 + t];
        } else if (k < 4) {
            int ci = k & 3;
            if (ci < 3) val = w1[co * 27 + ci * 9 + 8];
        }
        wpk1[ii] = bf16bits(val);
    }
}

// ---------------- MFMA conv1 3->64, fused BN stats + in-register x-pair max ----------------
__global__ __launch_bounds__(256) void conv1m_k(const float* __restrict__ in1,
                                                const float* __restrict__ in2,
                                                const unsigned short* __restrict__ wpk1,
                                                __hip_bfloat16* __restrict__ xpool,
                                                float* __restrict__ sums)
{
    constexpr int S = 84, P = P1, MBLK = 256, NB = 28, SPAN = MBLK + 2 * S + 2;  // 426
    __shared__ __align__(16) unsigned short ls4[SPAN * 4];   // 8 B per pixel [c0,c1,c2,0]
    __shared__ float qs[4][64], qs2[4][64];
    int img = blockIdx.x / NB;
    int p0 = (blockIdx.x % NB) * MBLK;
    int tid = threadIdx.x, lane = tid & 63, wv = tid >> 6;
    int col = lane & 15, quad = lane >> 4;
    const float* in = (img < NQ) ? in1 + (size_t)img * 3 * P1
                                 : in2 + (size_t)(img - NQ) * 3 * P1;
    for (int u = tid; u < SPAN; u += 256) {
        int p = p0 - S - 1 + u;
        union { unsigned short us[4]; uint2 u2; } o;
        o.u2 = (uint2){0u, 0u};
        if (p >= 0 && p < P) {
            o.us[0] = bf16bits(in[p]);
            o.us[1] = bf16bits(in[P1 + p]);
            o.us[2] = bf16bits(in[2 * P1 + p]);
        }
        *(uint2*)(ls4 + u * 4) = o.u2;
    }
    const short8* wb = (const short8*)wpk1;
    short8 b0[4], b1[4];
    #pragma unroll
    for (int nt = 0; nt < 4; ++nt) {
        b0[nt] = wb[(size_t)(nt * 64 + lane)];
        b1[nt] = wb[(size_t)((4 + nt) * 64 + lane)];
    }
    int t0 = 2 * quad, t1 = t0 + 1;
    int d0 = (t0 / 3 - 1) * S + (t0 % 3 - 1);
    int d1 = (t1 / 3 - 1) * S + (t1 % 3 - 1);
    const int d8 = S + 1;
    int tx0 = t0 % 3, tx1 = t1 % 3;
    __syncthreads();
    f32x4 acc[4][4];
    #pragma unroll
    for (int mt = 0; mt < 4; ++mt)
        #pragma unroll
        for (int nt = 0; nt < 4; ++nt) acc[mt][nt] = (f32x4){0.f, 0.f, 0.f, 0.f};
    #pragma unroll
    for (int mt = 0; mt < 4; ++mt) {
        int pl = wv * 64 + mt * 16 + col;
        int xm = (p0 + pl) % S;
        int base = pl + S + 1;
        uint2 h0 = *(const uint2*)(ls4 + (base + d0) * 4);
        uint2 h1 = *(const uint2*)(ls4 + (base + d1) * 4);
        uint2 h8 = *(const uint2*)(ls4 + (base + d8) * 4);
        bool ok0 = (tx0 == 0) ? (xm >= 1) : ((tx0 == 2) ? (xm <= S - 2) : true);
        bool ok1 = (tx1 == 0) ? (xm >= 1) : ((tx1 == 2) ? (xm <= S - 2) : true);
        bool ok8 = (quad == 0) && (xm <= S - 2);
        if (!ok0) h0 = (uint2){0u, 0u};
        if (!ok1) h1 = (uint2){0u, 0u};
        if (!ok8) h8 = (uint2){0u, 0u};
        union { uint4 u; short8 s; } ca, cb;
        ca.u = (uint4){h0.x, h0.y, h1.x, h1.y};
        cb.u = (uint4){h8.x, h8.y, 0u, 0u};
        #pragma unroll
        for (int nt = 0; nt < 4; ++nt) {
            acc[mt][nt] = __builtin_amdgcn_mfma_f32_16x16x32_bf16(ca.s, b0[nt], acc[mt][nt], 0, 0, 0);
            acc[mt][nt] = __builtin_amdgcn_mfma_f32_16x16x32_bf16(cb.s, b1[nt], acc[mt][nt], 0, 0, 0);
        }
    }
    float s[4] = {0.f, 0.f, 0.f, 0.f}, s2[4] = {0.f, 0.f, 0.f, 0.f};
    __hip_bfloat16* ob = xpool + (size_t)img * PX * 64;
    #pragma unroll
    for (int mt = 0; mt < 4; ++mt) {
        int tb = p0 + wv * 64 + mt * 16 + quad * 4;
        #pragma unroll
        for (int reg = 0; reg < 4; ++reg) {
            int pr = tb + reg;
            if (pr < P) {
                #pragma unroll
                for (int nt = 0; nt < 4; ++nt) {
                    float v = acc[mt][nt][reg];
                    s[nt] += v;
                    s2[nt] = fmaf(v, v, s2[nt]);
                }
            }
        }
        #pragma unroll
        for (int pr2 = 0; pr2 < 2; ++pr2) {
            int m0 = tb + pr2 * 2;
            if (m0 < P) {
                #pragma unroll
                for (int nt = 0; nt < 4; ++nt) {
                    float v = fmaxf(acc[mt][nt][pr2 * 2], acc[mt][nt][pr2 * 2 + 1]);
                    ob[(size_t)(m0 >> 1) * 64 + nt * 16 + col] = __float2bfloat16(v);
                }
            }
        }
    }
    #pragma unroll
    for (int d = 16; d < 64; d <<= 1)
        #pragma unroll
        for (int nt = 0; nt < 4; ++nt) {
            s[nt] += __shfl_xor(s[nt], d, 64);
            s2[nt] += __shfl_xor(s2[nt], d, 64);
        }
    if (quad == 0) {
        #pragma unroll
        for (int nt = 0; nt < 4; ++nt) {
            qs[wv][nt * 16 + col] = s[nt];
            qs2[wv][nt * 16 + col] = s2[nt];
        }
    }
    __syncthreads();
    if (wv == 0) {
        int g = (img < NQ) ? 0 : 1 + (img - NQ) / SHOT;
        int rep = blockIdx.x & (NREP - 1);
        float ts = qs[0][lane] + qs[1][lane] + qs[2][lane] + qs[3][lane];
        float ts2 = qs2[0][lane] + qs2[1][lane] + qs2[2][lane] + qs2[3][lane];
        float* base = sums + ((size_t)(g * 64 + lane) * 2) * NREP + rep;
        atomicAdd(base, ts);
        atomicAdd(base + NREP, ts2);
    }
}

// ------- MFMA conv 64->64. Staging MODE: 0 = raw bf16 copy; 1 = BN+LReLU on bf16 raw;
//         2 = y-pair max on x-pooled raw [2S x S] + BN + LReLU (fused bnpooly).
//         Output raw bf16; POOLX adds in-register x-pair max (out [P/2]).
template <int S, int MBLK, int MODE, bool POOLX>
__global__ __launch_bounds__(256) void conv64m_k(const unsigned short* __restrict__ inv,
                                                 const unsigned short* __restrict__ wpk,
                                                 __hip_bfloat16* __restrict__ out,
                                                 float* __restrict__ sums,
                                                 const float* __restrict__ msin)
{
    constexpr int P = S * S;
    constexpr int MT = MBLK / 64;
    constexpr int NB = (P + MBLK - 1) / MBLK;
    constexpr int SPAN = MBLK + 2 * S + 2;
    __shared__ __align__(16) unsigned short ls[SPAN * 72];
    __shared__ float qs[4][64], qs2[4][64];
    int img = blockIdx.x / NB;
    int p0 = (blockIdx.x % NB) * MBLK;
    int tid = threadIdx.x;
    int lane = tid & 63, wv = tid >> 6;
    int col = lane & 15, quad = lane >> 4;
    int g = (img < NQ) ? 0 : 1 + (img - NQ) / SHOT;
    if constexpr (MODE == 0) {
        const unsigned short* ib = inv + (size_t)img * P * 64;
        for (int u = tid; u < SPAN * 8; u += 256) {
            int pix = u >> 3, part = u & 7;
            int p = p0 - S - 1 + pix;
            short8 v = {0, 0, 0, 0, 0, 0, 0, 0};
            if (p >= 0 && p < P) v = *(const short8*)(ib + (size_t)p * 64 + part * 8);
            *(short8*)(ls + pix * 72 + part * 8) = v;
        }
    } else {
        int part = tid & 7;
        float ba[8], bb[8];
        #pragma unroll
        for (int j = 0; j < 8; ++j) {
            float2 ab = ((const float2*)msin)[g * 64 + part * 8 + j];
            ba[j] = ab.x;
            bb[j] = ab.y;
        }
        if constexpr (MODE == 1) {
            const unsigned short* ib = inv + (size_t)img * P * 64;
            for (int u = tid; u < SPAN * 8; u += 256) {
                int pix = u >> 3;
                int p = p0 - S - 1 + pix;
                union { unsigned short us[8]; short8 s8; } o;
                #pragma unroll
                for (int j = 0; j < 8; ++j) o.us[j] = 0;
                if (p >= 0 && p < P) {
                    union { short8 s8; unsigned short us[8]; } x;
                    x.s8 = *(const short8*)(ib + (size_t)p * 64 + part * 8);
                    #pragma unroll
                    for (int j = 0; j < 8; ++j) {
                        float v = fmaf(bits2f(x.us[j]), ba[j], bb[j]);
                        v = fmaxf(v, SLOPE * v);
                        o.us[j] = bf16bits(v);
                    }
                }
                *(short8*)(ls + pix * 72 + part * 8) = o.s8;
            }
        } else {
            // MODE 2: input is x-pooled raw of previous conv: [2S rows][S wide], 64ch
            const unsigned short* ib2 = inv + (size_t)img * (2 * (size_t)P) * 64;
            for (int u = tid; u < SPAN * 8; u += 256) {
                int pix = u >> 3;
                int p = p0 - S - 1 + pix;
                union { unsigned short us[8]; short8 s8; } o;
                #pragma unroll
                for (int j = 0; j < 8; ++j) o.us[j] = 0;
                if (p >= 0 && p < P) {
                    int y = p / S, x = p - y * S;
                    const unsigned short* src = ib2 + ((size_t)(2 * y) * S + x) * 64 + part * 8;
                    union { short8 s8; unsigned short us[8]; } x0, x1;
                    x0.s8 = *(const short8*)src;
                    x1.s8 = *(const short8*)(src + (size_t)S * 64);
                    #pragma unroll
                    for (int j = 0; j < 8; ++j) {
                        float v = fmaxf(bits2f(x0.us[j]), bits2f(x1.us[j]));
                        v = fmaf(v, ba[j], bb[j]);
                        v = fmaxf(v, SLOPE * v);
                        o.us[j] = bf16bits(v);
                    }
                }
                *(short8*)(ls + pix * 72 + part * 8) = o.s8;
            }
        }
    }
    __syncthreads();
    f32x4 acc[MT][4];
    #pragma unroll
    for (int mt = 0; mt < MT; ++mt)
        #pragma unroll
        for (int nt = 0; nt < 4; ++nt) acc[mt][nt] = (f32x4){0.f, 0.f, 0.f, 0.f};
    bool mok0[MT], mok2[MT];
    #pragma unroll
    for (int mt = 0; mt < MT; ++mt) {
        int xm = (p0 + wv * (MT * 16) + mt * 16 + col) % S;
        mok0[mt] = xm >= 1;
        mok2[mt] = xm <= S - 2;
    }
    const short8* wb = (const short8*)wpk;
    #pragma unroll
    for (int ky = 0; ky < 3; ++ky) {
        #pragma unroll
        for (int kx = 0; kx < 3; ++kx) {
            int t = ky * 3 + kx;
            int d = (ky - 1) * S + (kx - 1);
            #pragma unroll
            for (int half = 0; half < 2; ++half) {
                short8 b[4];
                #pragma unroll
                for (int nt = 0; nt < 4; ++nt)
                    b[nt] = wb[((t * 2 + half) * 4 + nt) * 64 + lane];
                #pragma unroll
                for (int mt = 0; mt < MT; ++mt) {
                    int idx = wv * (MT * 16) + mt * 16 + col + S + 1 + d;
                    short8 a = *(const short8*)(ls + idx * 72 + half * 32 + quad * 8);
                    bool ok = (kx == 0) ? mok0[mt] : (kx == 2) ? mok2[mt] : true;
                    if (!ok) a = (short8){0, 0, 0, 0, 0, 0, 0, 0};
                    #pragma unroll
                    for (int nt = 0; nt < 4; ++nt)
                        acc[mt][nt] = __builtin_amdgcn_mfma_f32_16x16x32_bf16(a, b[nt], acc[mt][nt], 0, 0, 0);
                }
            }
        }
    }
    float s[4] = {0.f, 0.f, 0.f, 0.f}, s2[4] = {0.f, 0.f, 0.f, 0.f};
    __hip_bfloat16* ob = out + (size_t)img * (POOLX ? P / 2 : P) * 64;
    #pragma unroll
    for (int mt = 0; mt < MT; ++mt) {
        int tb = p0 + wv * (MT * 16) + mt * 16 + quad * 4;
        #pragma unroll
        for (int reg = 0; reg < 4; ++reg) {
            int pr = tb + reg;
            if (pr < P) {
                #pragma unroll
                for (int nt = 0; nt < 4; ++nt) {
                    float v = acc[mt][nt][reg];
                    s[nt] += v;
                    s2[nt] = fmaf(v, v, s2[nt]);
                }
            }
        }
        if constexpr (POOLX) {
            #pragma unroll
            for (int pr2 = 0; pr2 < 2; ++pr2) {
                int m0 = tb + pr2 * 2;
                if (m0 < P) {
                    #pragma unroll
                    for (int nt = 0; nt < 4; ++nt) {
                        float v = fmaxf(acc[mt][nt][pr2 * 2], acc[mt][nt][pr2 * 2 + 1]);
                        ob[(size_t)(m0 >> 1) * 64 + nt * 16 + col] = __float2bfloat16(v);
                    }
                }
            }
        } else {
            #pragma unroll
            for (int reg = 0; reg < 4; ++reg) {
                int pr = tb + reg;
                if (pr < P) {
                    #pragma unroll
                    for (int nt = 0; nt < 4; ++nt)
                        ob[(size_t)pr * 64 + nt * 16 + col] = __float2bfloat16(acc[mt][nt][reg]);
                }
            }
        }
    }
    #pragma unroll
    for (int d = 16; d < 64; d <<= 1)
        #pragma unroll
        for (int nt = 0; nt < 4; ++nt) {
            s[nt] += __shfl_xor(s[nt], d, 64);
            s2[nt] += __shfl_xor(s2[nt], d, 64);
        }
    if (quad == 0) {
        #pragma unroll
        for (int nt = 0; nt < 4; ++nt) {
            qs[wv][nt * 16 + col] = s[nt];
            qs2[wv][nt * 16 + col] = s2[nt];
        }
    }
    __syncthreads();
    if (wv == 0) {
        int rep = blockIdx.x & (NREP - 1);
        float ts = qs[0][lane] + qs[1][lane] + qs[2][lane] + qs[3][lane];
        float ts2 = qs2[0][lane] + qs2[1][lane] + qs2[2][lane] + qs2[3][lane];
        float* base = sums + ((size_t)(g * 64 + lane) * 2) * NREP + rep;
        atomicAdd(base, ts);
        atomicAdd(base + NREP, ts2);
    }
}

// fold (mean, invstd, gamma, beta) -> (a, b): y = x*a + b   (sums has NREP replicas)
__global__ void finalize_k(const float* __restrict__ sums, float* __restrict__ ms,
                           const float* __restrict__ gamma, const float* __restrict__ beta, int P)
{
    int i = blockIdx.x * blockDim.x + threadIdx.x;
    if (i >= 6 * 64) return;
    int g = i >> 6, c = i & 63;
    const float* ps = sums + (size_t)i * 2 * NREP;
    float s = 0.f, s2 = 0.f;
    #pragma unroll
    for (int r = 0; r < NREP; ++r) { s += ps[r]; s2 += ps[NREP + r]; }
    float cnt = (float)((g == 0 ? NQ : SHOT) * P);
    float mean = s / cnt;
    float var = s2 / cnt - mean * mean;
    float a = rsqrtf(var + EPSB) * gamma[c];
    ms[i * 2] = a;
    ms[i * 2 + 1] = fmaf(-mean, a, beta[c]);
}

// ---------------- BN4 + LeakyReLU + per-pixel L2-normalize on bf16 raw -> bf16 -------------
__global__ __launch_bounds__(256) void bnnorm_k(const unsigned short* __restrict__ x,
                                                const float* __restrict__ ms,
                                                __hip_bfloat16* __restrict__ out)
{
    int lane = threadIdx.x & 63, wvr = threadIdx.x >> 6;
    int pix = blockIdx.x * 4 + wvr;        // one wave per pixel
    if (pix >= NIMG * P3) return;
    int img = pix / P3;
    int g = (img < NQ) ? 0 : 1 + (img - NQ) / SHOT;
    float v = fmaf(bits2f(x[(size_t)pix * 64 + lane]), ms[(g * 64 + lane) * 2], ms[(g * 64 + lane) * 2 + 1]);
    v = v >= 0.f ? v : SLOPE * v;
    float ss = v * v;
    #pragma unroll
    for (int d = 32; d > 0; d >>= 1) ss += __shfl_xor(ss, d, 64);
    out[(size_t)pix * 64 + lane] = __float2bfloat16(v * rsqrtf(ss));
}

// ---------------- similarity: m-split blocks, 64-row chunks, partial top-3 + merge ---------
__device__ __forceinline__ void ins3(float v, float& t0, float& t1, float& t2)
{
    float n1 = __builtin_amdgcn_fmed3f(v, t0, t1);
    float n2 = __builtin_amdgcn_fmed3f(v, t1, t2);
    t0 = fmaxf(t0, v);
    t1 = n1;
    t2 = n2;
}

// grid: bq(32) x n(5) x qb(7) x mr(4) = 4480 blocks; block: 64q (wave=16q) x 576-row m-range
__global__ __launch_bounds__(256, 6) void sim_part_k(const __hip_bfloat16* __restrict__ fhat,
                                                     float* __restrict__ part)
{
    __shared__ __align__(16) unsigned short sl[64 * SLS];  // 64 m-rows, SLS-ushort stride
    int t = blockIdx.x;
    int mr = t & 3;
    int qb = (t >> 2) % 7;
    int n = (t / 28) % NCLS;
    int bq = t / (28 * NCLS);
    int tid = threadIdx.x, lane = tid & 63, wv = tid >> 6;
    int col = lane & 15, quad = lane >> 4;
    int q = qb * 64 + wv * 16 + col;
    int qc = q < P3 ? q : P3 - 1;
    const unsigned short* qp = (const unsigned short*)fhat + ((size_t)bq * P3 + qc) * 64;
    short8 a0 = *(const short8*)(qp + quad * 8);
    short8 a1 = *(const short8*)(qp + 32 + quad * 8);
    const unsigned short* sp = (const unsigned short*)fhat + (size_t)(NQ + n * SHOT) * P3 * 64;
    int m_lo = mr * MSPAN;
    int m_cnt = MM - m_lo; if (m_cnt > MSPAN) m_cnt = MSPAN;
    int nch = (m_cnt + 63) >> 6;
    float t0[4], t1[4], t2[4];
    #pragma unroll
    for (int r = 0; r < 4; ++r) { t0[r] = NEGINF; t1[r] = NEGINF; t2[r] = NEGINF; }
    int srow = tid >> 3, scc = (tid & 7) * 8;
    for (int c = 0; c < nch; ++c) {
        int m0 = m_lo + c * 64;
        __syncthreads();
        #pragma unroll
        for (int pass = 0; pass < 2; ++pass) {
            int row = srow + pass * 32;
            int m = m0 + row;
            short8 vv = {0, 0, 0, 0, 0, 0, 0, 0};
            if (m < MM) vv = *(const short8*)(sp + (size_t)m * 64 + scc);
            *(short8*)(sl + row * SLS + scc) = vv;
        }
        __syncthreads();
        const unsigned short* sr = sl + col * SLS + quad * 8;
        #pragma unroll
        for (int mt = 0; mt < 4; ++mt) {
            if (m0 + mt * 16 < MM) {            // wave-uniform: skip fully-fake tiles
                short8 b0 = *(const short8*)(sr);
                short8 b1 = *(const short8*)(sr + 32);
                f32x4 acc = {0.f, 0.f, 0.f, 0.f};
                acc = __builtin_amdgcn_mfma_f32_16x16x32_bf16(a0, b0, acc, 0, 0, 0);
                acc = __builtin_amdgcn_mfma_f32_16x16x32_bf16(a1, b1, acc, 0, 0, 0);
                #pragma unroll
                for (int r = 0; r < 4; ++r) ins3(acc[r], t0[r], t1[r], t2[r]);
            }
            sr += 16 * SLS;
        }
    }
    #pragma unroll
    for (int d = 1; d < 16; d <<= 1)
        #pragma unroll
        for (int r = 0; r < 4; ++r) {
            float u0 = __shfl_xor(t0[r], d, 64);
            float u1 = __shfl_xor(t1[r], d, 64);
            float u2 = __shfl_xor(t2[r], d, 64);
            ins3(u0, t0[r], t1[r], t2[r]);
            ins3(u1, t0[r], t1[r], t2[r]);
            ins3(u2, t0[r], t1[r], t2[r]);
        }
    if (col == 0) {
        #pragma unroll
        for (int r = 0; r < 4; ++r) {
            int ql = wv * 16 + quad * 4 + r;
            float* pp = part + ((((size_t)(bq * NCLS + n) * 7 + qb) * 4 + mr) * 64 + ql) * 3;
            pp[0] = t0[r];
            pp[1] = t1[r];
            pp[2] = t2[r];
        }
    }
}

// one block per (bq, n): merge 4 m-range partials per q, sum top-3, write out directly
__global__ __launch_bounds__(256) void sim_merge_k(const float* __restrict__ part,
                                                   float* __restrict__ out)
{
    __shared__ float red[4];
    int b = blockIdx.x;                    // bq*NCLS + n
    int tid = threadIdx.x, lane = tid & 63, wv = tid >> 6;
    float s = 0.f;
    for (int q = tid; q < P3; q += 256) {
        int qb = q >> 6, ql = q & 63;
        const float* pp = part + (((size_t)b * 7 + qb) * 4 * 64 + ql) * 3;
        float v0 = pp[0], v1 = pp[1], v2 = pp[2];
        #pragma unroll
        for (int mr = 1; mr < 4; ++mr) {
            const float* pm = pp + (size_t)mr * 192;
            ins3(pm[0], v0, v1, v2);
            ins3(pm[1], v0, v1, v2);
            ins3(pm[2], v0, v1, v2);
        }
        s += v0 + v1 + v2;
    }
    #pragma unroll
    for (int d = 32; d > 0; d >>= 1) s += __shfl_xor(s, d, 64);
    if (lane == 0) red[wv] = s;
    __syncthreads();
    if (tid == 0) out[b] = red[0] + red[1] + red[2] + red[3];
}

extern "C" void kernel_launch(void* const* d_in, const int* in_sizes, int n_in,
                              void* d_out, int out_size, void* d_ws, size_t ws_size,
                              hipStream_t stream)
{
    const float* input1 = (const float*)d_in[0];
    const float* input2 = (const float*)d_in[1];
    const float* w1 = (const float*)d_in[2];
    const float* g1 = (const float*)d_in[3];
    const float* b1 = (const float*)d_in[4];
    const float* w2 = (const float*)d_in[5];
    const float* g2 = (const float*)d_in[6];
    const float* b2 = (const float*)d_in[7];
    const float* w3 = (const float*)d_in[8];
    const float* g3 = (const float*)d_in[9];
    const float* b3 = (const float*)d_in[10];
    const float* w4 = (const float*)d_in[11];
    const float* g4 = (const float*)d_in[12];
    const float* b4 = (const float*)d_in[13];
    float* out = (float*)d_out;

    char* w8 = (char*)d_ws;
    const size_t oB = 51480576;
    const size_t oT = oB + 12870144;
    const size_t STG = 6 * 64 * 2 * NREP * sizeof(float);   // 98304 B per stage
    __hip_bfloat16* xpool1 = (__hip_bfloat16*)(w8 + 0);     // [57][3528][64] bf16 25.7MB
    __hip_bfloat16* conv3raw = (__hip_bfloat16*)(w8 + 0);   // reuse A: [57][441][64] bf16 3.2MB
    __hip_bfloat16* conv4raw = (__hip_bfloat16*)(w8 + 9652608);  // 3.2MB bf16
    __hip_bfloat16* fhat = (__hip_bfloat16*)(w8 + 16087680);
    __hip_bfloat16* xpool2 = (__hip_bfloat16*)(w8 + oB);    // [57][882][64] bf16 6.44MB
    float* sums = (float*)(w8 + oT);                        // 4 stages x 98304 B
    float* ms = (float*)(w8 + oT + 4 * STG);
    unsigned short* wpk2 = (unsigned short*)(w8 + oT + 4 * STG + 12288);
    unsigned short* wpk3 = (unsigned short*)(w8 + oT + 4 * STG + 12288 + 73728);
    unsigned short* wpk4 = (unsigned short*)(w8 + oT + 4 * STG + 12288 + 147456);
    unsigned short* wpk1 = (unsigned short*)(w8 + oT + 4 * STG + 12288 + 221184);
    const size_t oP = oT + 4 * STG + 12288 + 221184 + 8192;
    float* part = (float*)(w8 + oP);                        // 32*5*7*4*64*3 f32 = 3.44MB
    if (ws_size < oP + (size_t)NQ * NCLS * 7 * MRNG * 64 * 3 * sizeof(float)) return;
    float* sums1 = sums;
    float* sums2 = sums + 6 * 64 * 2 * NREP;
    float* sums3 = sums2 + 6 * 64 * 2 * NREP;
    float* sums4 = sums3 + 6 * 64 * 2 * NREP;

    // pack weights + zero stats (no memsets needed; sim_merge overwrites all of d_out)
    pack_all_k<<<448, 256, 0, stream>>>(w1, w2, w3, w4, wpk1, wpk2, wpk3, wpk4, sums);

    // stage 1: conv1 MFMA + in-register x-pool (+stats) -> finalize
    conv1m_k<<<NIMG * 28, 256, 0, stream>>>(input1, input2, wpk1, xpool1, sums1);
    finalize_k<<<2, 256, 0, stream>>>(sums1, ms + 0, g1, b1, P1);
    // stage 2: conv2 with y-pool+BN1+LReLU fused into staging, x-pool epilogue (+stats)
    conv64m_k<42, 256, 2, true><<<NIMG * 7, 256, 0, stream>>>(
        (const unsigned short*)xpool1, wpk2, xpool2, sums2, ms + 0);
    finalize_k<<<2, 256, 0, stream>>>(sums2, ms + 768, g2, b2, P2);
    // stage 3: conv3 with y-pool+BN2+LReLU fused into staging (+stats, bf16 raw out)
    conv64m_k<21, 128, 2, false><<<NIMG * 4, 256, 0, stream>>>(
        (const unsigned short*)xpool2, wpk3, conv3raw, sums3, ms + 768);
    finalize_k<<<2, 256, 0, stream>>>(sums3, ms + 1536, g3, b3, P3);
    // stage 4: conv4 with BN3+LReLU fused into staging (+stats, bf16 raw out)
    conv64m_k<21, 128, 1, false><<<NIMG * 4, 256, 0, stream>>>(
        (const unsigned short*)conv3raw, wpk4, conv4raw, sums4, ms + 1536);
    finalize_k<<<2, 256, 0, stream>>>(sums4, ms + 2304, g4, b4, P3);
    bnnorm_k<<<6285, 256, 0, stream>>>((const unsigned short*)conv4raw, ms + 2304, fhat);
    // similarity: partial top-3 over m-ranges, then merge (writes d_out directly)
    sim_part_k<<<NQ * NCLS * 7 * MRNG, 256, 0, stream>>>(fhat, part);
    sim_merge_k<<<NQ * NCLS, 256, 0, stream>>>(part, out);
}